// Round 2
// baseline (1024.914 us; speedup 1.0000x reference)
//
#include <hip/hip_runtime.h>

#define DEVINL __device__ __forceinline__

constexpr int N_SITES = 500000;
constexpr int C1 = 128;
constexpr int CH = 64;
constexpr int C2 = 128;
constexpr float BN_EPS = 1e-5f;
constexpr int NT32 = N_SITES / 32;   // 15625 tiles of 32 sites (exact)

typedef __attribute__((ext_vector_type(4))) float f32x4;
typedef __attribute__((ext_vector_type(8))) short s16x8;

DEVINL float bf2f(unsigned short s) { return __uint_as_float(((unsigned)s) << 16); }
DEVINL unsigned short f2bf(float f) {
  unsigned u = __float_as_uint(f);
  return (unsigned short)((u + 0x7fffu + ((u >> 16) & 1u)) >> 16);  // RNE
}
DEVINL float silu_f(float x) { return x / (1.0f + __expf(-x)); }

template<bool F32>
DEVINL float rdf(const void* p, long i) {
  if constexpr (F32) return ((const float*)p)[i];
  else return bf2f(((const unsigned short*)p)[i]);
}

DEVINL bool probe_f32(const void* buf) {
  unsigned w = ((const unsigned*)buf)[threadIdx.x & 63];
  unsigned e = (w >> 7) & 0xFFu;
  bool bf_like = (e >= 90u && e <= 134u) || ((w & 0xFFFFu) == 0u);
  return __popcll(__ballot(bf_like)) < 48;
}
DEVINL bool probe_i64(const int* nbr) {
  int v = nbr[2 * (threadIdx.x & 63) + 1];
  return __popcll(__ballot(v == 0)) == 64;
}
template<bool I64>
DEVINL int rd_idx(const int* nbr, long ofs) {
  if constexpr (I64) return nbr[2 * ofs];
  else return nbr[ofs];
}

DEVINL s16x8 as_s16x8(uint4 v) { union { uint4 u; s16x8 s; } c; c.u = v; return c.s; }

DEVINL s16x8 pack8(float a0, float a1, float a2, float a3,
                   float a4, float a5, float a6, float a7) {
  uint4 r;
  r.x = (unsigned)f2bf(a0) | ((unsigned)f2bf(a1) << 16);
  r.y = (unsigned)f2bf(a2) | ((unsigned)f2bf(a3) << 16);
  r.z = (unsigned)f2bf(a4) | ((unsigned)f2bf(a5) << 16);
  r.w = (unsigned)f2bf(a6) | ((unsigned)f2bf(a7) << 16);
  return as_s16x8(r);
}

// Swapped-operand MFMA: D = A*B with A = W^T (m = out-channel), B = data^T
// (n = site).  D layout: lane holds site = lane&15, channels (lane>>4)*4+q
// -> 4 CONSECUTIVE channels per lane => vectorized epilogues.
DEVINL f32x4 mfma16(s16x8 a, s16x8 b, f32x4 c) {
  return __builtin_amdgcn_mfma_f32_16x16x32_bf16(a, b, c, 0, 0, 0);
}

// Fragment packing (shared by all stagers):
// element (k, n) of a [K][M] weight slab -> frag (kk = k>>5, mt = n>>4),
// lane = ((k>>3)&3)*16 + (n&15), j = k&7.  One frag = 64 lanes x 8 bf16 = 1KB,
// read back as a single conflict-free ds_read_b128 per lane.

// ---------------------------------------------------------------------------
// K1: h = silu(bn1(features @ W1)), h bf16 [N][64].
// W1^T as A-fragments (BN scale folded in), feat rows as B-fragments.
// ---------------------------------------------------------------------------
template<bool F32>
DEVINL void cv1_body(const void* feat, const void* W1,
                     const void* g1, const void* b1, const void* m1, const void* v1,
                     unsigned short* __restrict__ h,
                     unsigned short* lw1, float* lsc, float* ltb)
{
  const int tid = threadIdx.x;
  for (int n = tid; n < CH; n += 256) {
    float s = rdf<F32>(g1, n) * rsqrtf(rdf<F32>(v1, n) + BN_EPS);
    lsc[n] = s;
    ltb[n] = rdf<F32>(b1, n) - rdf<F32>(m1, n) * s;
  }
  __syncthreads();
  for (int idx = tid; idx < C1 * CH; idx += 256) {
    int k = idx >> 6, n = idx & 63;
    int frag = (k >> 5) * 4 + (n >> 4);
    int ln = (((k >> 3) & 3) << 4) | (n & 15);
    lw1[(frag * 64 + ln) * 8 + (k & 7)] = f2bf(rdf<F32>(W1, idx) * lsc[n]);
  }
  __syncthreads();

  const int lane = tid & 63, w = tid >> 6;
  const int lr = lane & 15, lg = lane >> 4;
  const s16x8* lw1s = (const s16x8*)lw1;
  s16x8 aw[4][4];
#pragma unroll
  for (int kk = 0; kk < 4; ++kk)
#pragma unroll
    for (int mt = 0; mt < 4; ++mt)
      aw[kk][mt] = lw1s[(kk * 4 + mt) * 64 + lane];

  const int stride = gridDim.x * 4;
  for (int tile = blockIdx.x * 4 + w; tile < NT32; tile += stride) {
    const long base = (long)tile * 32;
    f32x4 acc[2][4];
#pragma unroll
    for (int st = 0; st < 2; ++st)
#pragma unroll
      for (int mt = 0; mt < 4; ++mt) acc[st][mt] = (f32x4)0.0f;

#pragma unroll
    for (int st = 0; st < 2; ++st) {
      const long row = base + st * 16 + lr;
#pragma unroll
      for (int kk = 0; kk < 4; ++kk) {
        s16x8 b;
        if constexpr (F32) {
          const float* fp = (const float*)feat + row * C1 + kk * 32 + lg * 8;
          float4 f0 = ((const float4*)fp)[0];
          float4 f1 = ((const float4*)fp)[1];
          b = pack8(f0.x, f0.y, f0.z, f0.w, f1.x, f1.y, f1.z, f1.w);
        } else {
          b = as_s16x8(*(const uint4*)((const unsigned short*)feat + row * C1 + kk * 32 + lg * 8));
        }
#pragma unroll
        for (int mt = 0; mt < 4; ++mt)
          acc[st][mt] = mfma16(aw[kk][mt], b, acc[st][mt]);
      }
    }
#pragma unroll
    for (int st = 0; st < 2; ++st) {
      const size_t site = (size_t)(base + st * 16 + lr);
#pragma unroll
      for (int mt = 0; mt < 4; ++mt) {
        int ch4 = mt * 16 + lg * 4;
        f32x4 tb = *(const f32x4*)&ltb[ch4];
        f32x4 v = acc[st][mt];
        ushort4 hv;
        hv.x = f2bf(silu_f(v[0] + tb[0]));
        hv.y = f2bf(silu_f(v[1] + tb[1]));
        hv.z = f2bf(silu_f(v[2] + tb[2]));
        hv.w = f2bf(silu_f(v[3] + tb[3]));
        *(ushort4*)(h + site * CH + ch4) = hv;
      }
    }
  }
}

__global__ __launch_bounds__(256, 3) void k_cv1(
    const void* feat, const void* W1,
    const void* g1, const void* b1, const void* m1, const void* v1,
    unsigned short* __restrict__ h, unsigned short* __restrict__ zrow)
{
  __shared__ __align__(16) unsigned short lw1[16 * 64 * 8];  // 16 KiB
  __shared__ __align__(16) float lsc[CH];
  __shared__ __align__(16) float ltb[CH];
  if (blockIdx.x == 0 && threadIdx.x < 8)
    ((uint4*)zrow)[threadIdx.x] = make_uint4(0u, 0u, 0u, 0u);
  if (probe_f32(feat)) cv1_body<true >(feat, W1, g1, b1, m1, v1, h, lw1, lsc, ltb);
  else                 cv1_body<false>(feat, W1, g1, b1, m1, v1, h, lw1, lsc, ltb);
}

// ---------------------------------------------------------------------------
// K2: t = silu(bn2( sum_{k=0..8} gather(h, nbr[k]) @ W2[k] )), t bf16 [N][64].
// W2^T (scale-folded) as A-fragments in LDS; gathered h rows as B-fragments.
// 512-thread blocks: 74 KB LDS -> 2 blocks/CU -> 16 waves/CU.
// ---------------------------------------------------------------------------
template<bool F32, bool I64>
DEVINL void cv2_body(const unsigned short* __restrict__ h, const int* __restrict__ nbr,
                     const void* W2,
                     const void* g2, const void* b2, const void* m2, const void* v2,
                     unsigned short* __restrict__ t,
                     const unsigned short* __restrict__ zrow,
                     unsigned short* lw2, float* lsc, float* ltb)
{
  const int tid = threadIdx.x;
  for (int n = tid; n < CH; n += 512) {
    float s = rdf<F32>(g2, n) * rsqrtf(rdf<F32>(v2, n) + BN_EPS);
    lsc[n] = s;
    ltb[n] = rdf<F32>(b2, n) - rdf<F32>(m2, n) * s;
  }
  __syncthreads();
  for (int idx = tid; idx < 9 * CH * CH; idx += 512) {
    int tap = idx >> 12;
    int k = (idx >> 6) & 63, n = idx & 63;
    int frag = (tap * 2 + (k >> 5)) * 4 + (n >> 4);
    int ln = (((k >> 3) & 3) << 4) | (n & 15);
    lw2[(frag * 64 + ln) * 8 + (k & 7)] = f2bf(rdf<F32>(W2, (long)idx) * lsc[n]);
  }
  __syncthreads();

  const int lane = tid & 63, w = tid >> 6;   // w in [0,8)
  const int lr = lane & 15, lg = lane >> 4;
  const s16x8* lw2s = (const s16x8*)lw2;

  const int stride = gridDim.x * 8;
  for (int tile = blockIdx.x * 8 + w; tile < NT32; tile += stride) {
    const long base = (long)tile * 32;
    f32x4 acc[2][4];
#pragma unroll
    for (int st = 0; st < 2; ++st)
#pragma unroll
      for (int mt = 0; mt < 4; ++mt) acc[st][mt] = (f32x4)0.0f;

#pragma unroll
    for (int tap = 0; tap < 9; ++tap) {
      int i0 = rd_idx<I64>(nbr, (long)tap * N_SITES + base + lr);
      int i1 = rd_idx<I64>(nbr, (long)tap * N_SITES + base + 16 + lr);
      const unsigned short* s0 = (i0 == N_SITES) ? zrow : h + (size_t)i0 * CH;
      const unsigned short* s1 = (i1 == N_SITES) ? zrow : h + (size_t)i1 * CH;
      s16x8 b00 = as_s16x8(*(const uint4*)(s0 + lg * 8));        // st=0, kk=0
      s16x8 b01 = as_s16x8(*(const uint4*)(s0 + 32 + lg * 8));   // st=0, kk=1
      s16x8 b10 = as_s16x8(*(const uint4*)(s1 + lg * 8));
      s16x8 b11 = as_s16x8(*(const uint4*)(s1 + 32 + lg * 8));
#pragma unroll
      for (int mt = 0; mt < 4; ++mt) {
        s16x8 a0 = lw2s[((tap * 2 + 0) * 4 + mt) * 64 + lane];
        s16x8 a1 = lw2s[((tap * 2 + 1) * 4 + mt) * 64 + lane];
        acc[0][mt] = mfma16(a0, b00, acc[0][mt]);
        acc[0][mt] = mfma16(a1, b01, acc[0][mt]);
        acc[1][mt] = mfma16(a0, b10, acc[1][mt]);
        acc[1][mt] = mfma16(a1, b11, acc[1][mt]);
      }
    }
#pragma unroll
    for (int st = 0; st < 2; ++st) {
      const size_t site = (size_t)(base + st * 16 + lr);
#pragma unroll
      for (int mt = 0; mt < 4; ++mt) {
        int ch4 = mt * 16 + lg * 4;
        f32x4 tb = *(const f32x4*)&ltb[ch4];
        f32x4 v = acc[st][mt];
        ushort4 tv;
        tv.x = f2bf(silu_f(v[0] + tb[0]));
        tv.y = f2bf(silu_f(v[1] + tb[1]));
        tv.z = f2bf(silu_f(v[2] + tb[2]));
        tv.w = f2bf(silu_f(v[3] + tb[3]));
        *(ushort4*)(t + site * CH + ch4) = tv;
      }
    }
  }
}

__global__ __launch_bounds__(512, 4) void k_cv2(
    const unsigned short* __restrict__ h, const int* __restrict__ nbr,
    const void* W2,
    const void* g2, const void* b2, const void* m2, const void* v2,
    unsigned short* __restrict__ t, const unsigned short* __restrict__ zrow)
{
  __shared__ __align__(16) unsigned short lw2[72 * 64 * 8];  // 73728 B
  __shared__ __align__(16) float lsc[CH];
  __shared__ __align__(16) float ltb[CH];
  bool f32 = probe_f32(W2);
  bool i64 = probe_i64(nbr);
  if (f32) { if (i64) cv2_body<true , true >(h, nbr, W2, g2, b2, m2, v2, t, zrow, lw2, lsc, ltb);
             else     cv2_body<true , false>(h, nbr, W2, g2, b2, m2, v2, t, zrow, lw2, lsc, ltb); }
  else     { if (i64) cv2_body<false, true >(h, nbr, W2, g2, b2, m2, v2, t, zrow, lw2, lsc, ltb);
             else     cv2_body<false, false>(h, nbr, W2, g2, b2, m2, v2, t, zrow, lw2, lsc, ltb); }
}

// ---------------------------------------------------------------------------
// K3: out = silu( bn3(t @ W3) + features ).  W3^T (scale-folded) as
// A-fragments in LDS; t rows as B-fragments.  M split in halves to keep
// VGPR <= 128 (4 waves/SIMD).  Fully vectorized float4 epilogue.
// ---------------------------------------------------------------------------
template<bool F32>
DEVINL void cv3_body(const unsigned short* __restrict__ t, const void* W3,
                     const void* feat,
                     const void* g3, const void* b3, const void* m3, const void* v3,
                     void* out, unsigned short* lw3, float* lsc, float* ltb)
{
  const int tid = threadIdx.x;
  for (int n = tid; n < C2; n += 256) {
    float s = rdf<F32>(g3, n) * rsqrtf(rdf<F32>(v3, n) + BN_EPS);
    lsc[n] = s;
    ltb[n] = rdf<F32>(b3, n) - rdf<F32>(m3, n) * s;
  }
  __syncthreads();
  for (int idx = tid; idx < CH * C2; idx += 256) {
    int k = idx >> 7, n = idx & 127;
    int frag = (k >> 5) * 8 + (n >> 4);
    int ln = (((k >> 3) & 3) << 4) | (n & 15);
    lw3[(frag * 64 + ln) * 8 + (k & 7)] = f2bf(rdf<F32>(W3, (long)idx) * lsc[n]);
  }
  __syncthreads();

  const int lane = tid & 63, w = tid >> 6;
  const int lr = lane & 15, lg = lane >> 4;
  const s16x8* lw3s = (const s16x8*)lw3;

  const int stride = gridDim.x * 4;
  for (int tile = blockIdx.x * 4 + w; tile < NT32; tile += stride) {
    const long base = (long)tile * 32;
    // B fragments: t rows (site = base + st*16 + lr)
    s16x8 bfr[2][2];
#pragma unroll
    for (int st = 0; st < 2; ++st) {
      const size_t row = (size_t)(base + st * 16 + lr);
      bfr[st][0] = as_s16x8(*(const uint4*)(t + row * CH + lg * 8));
      bfr[st][1] = as_s16x8(*(const uint4*)(t + row * CH + 32 + lg * 8));
    }
#pragma unroll
    for (int half = 0; half < 2; ++half) {
      s16x8 a[2][4];
#pragma unroll
      for (int kk = 0; kk < 2; ++kk)
#pragma unroll
        for (int m = 0; m < 4; ++m)
          a[kk][m] = lw3s[(kk * 8 + half * 4 + m) * 64 + lane];
      f32x4 acc[2][4];
#pragma unroll
      for (int st = 0; st < 2; ++st)
#pragma unroll
        for (int m = 0; m < 4; ++m) acc[st][m] = (f32x4)0.0f;
#pragma unroll
      for (int st = 0; st < 2; ++st)
#pragma unroll
        for (int kk = 0; kk < 2; ++kk)
#pragma unroll
          for (int m = 0; m < 4; ++m)
            acc[st][m] = mfma16(a[kk][m], bfr[st][kk], acc[st][m]);
#pragma unroll
      for (int st = 0; st < 2; ++st) {
        const size_t site = (size_t)(base + st * 16 + lr);
#pragma unroll
        for (int m = 0; m < 4; ++m) {
          int ch4 = (half * 4 + m) * 16 + lg * 4;
          f32x4 tb = *(const f32x4*)&ltb[ch4];
          f32x4 v = acc[st][m];
          float f0, f1, f2v, f3;
          if constexpr (F32) {
            float4 fv = *(const float4*)((const float*)feat + site * C1 + ch4);
            f0 = fv.x; f1 = fv.y; f2v = fv.z; f3 = fv.w;
          } else {
            const unsigned short* fp = (const unsigned short*)feat + site * C1 + ch4;
            ushort4 fu = *(const ushort4*)fp;
            f0 = bf2f(fu.x); f1 = bf2f(fu.y); f2v = bf2f(fu.z); f3 = bf2f(fu.w);
          }
          float r0 = silu_f(v[0] + tb[0] + f0);
          float r1 = silu_f(v[1] + tb[1] + f1);
          float r2 = silu_f(v[2] + tb[2] + f2v);
          float r3 = silu_f(v[3] + tb[3] + f3);
          if constexpr (F32) {
            float4 ov; ov.x = r0; ov.y = r1; ov.z = r2; ov.w = r3;
            *(float4*)((float*)out + site * C2 + ch4) = ov;
          } else {
            ushort4 ov;
            ov.x = f2bf(r0); ov.y = f2bf(r1); ov.z = f2bf(r2); ov.w = f2bf(r3);
            *(ushort4*)((unsigned short*)out + site * C2 + ch4) = ov;
          }
        }
      }
    }
  }
}

__global__ __launch_bounds__(256, 4) void k_cv3(
    const unsigned short* __restrict__ t, const void* W3, const void* feat,
    const void* g3, const void* b3, const void* m3, const void* v3,
    void* out)
{
  __shared__ __align__(16) unsigned short lw3[16 * 64 * 8];  // 16 KiB
  __shared__ __align__(16) float lsc[C2];
  __shared__ __align__(16) float ltb[C2];
  if (probe_f32(feat)) cv3_body<true >(t, W3, feat, g3, b3, m3, v3, out, lw3, lsc, ltb);
  else                 cv3_body<false>(t, W3, feat, g3, b3, m3, v3, out, lw3, lsc, ltb);
}

// ---------------------------------------------------------------------------
extern "C" void kernel_launch(void* const* d_in, const int* in_sizes, int n_in,
                              void* d_out, int out_size, void* d_ws, size_t ws_size,
                              hipStream_t stream)
{
  (void)out_size; (void)ws_size;
  // dict order: feat(64e6B) nbr W1 W2 W3 g1 b1 m1 v1 g2 b2 m2 v2 g3 b3 m3 v3
  int mp[17];
  for (int i = 0; i < 17; ++i) mp[i] = i;
  if (n_in == 17 && in_sizes[0] != 64000000 &&
      in_sizes[6] == 64000000 && in_sizes[13] == 4500000) {
    const int amap[17] = {6, 13, 0, 1, 2, 7, 3, 10, 14, 8, 4, 11, 15, 9, 5, 12, 16};
    for (int i = 0; i < 17; ++i) mp[i] = amap[i];
  }
  const void* feat = d_in[mp[0]];
  const int*  nbr  = (const int*)d_in[mp[1]];
  const void* W1 = d_in[mp[2]];
  const void* W2 = d_in[mp[3]];
  const void* W3 = d_in[mp[4]];
  const void* g1 = d_in[mp[5]],  *b1 = d_in[mp[6]],  *m1 = d_in[mp[7]],  *v1 = d_in[mp[8]];
  const void* g2 = d_in[mp[9]],  *b2 = d_in[mp[10]], *m2 = d_in[mp[11]], *v2 = d_in[mp[12]];
  const void* g3 = d_in[mp[13]], *b3 = d_in[mp[14]], *m3 = d_in[mp[15]], *v3 = d_in[mp[16]];

  // workspace: h = N*64 bf16 (64,000,000 B), t = N*64 bf16 (64,000,000 B)
  unsigned short* h = (unsigned short*)d_ws;
  unsigned short* t = (unsigned short*)((char*)d_ws + (size_t)N_SITES * CH * 2);
  // 128B zero row for sentinel gathers at start of d_out (zeroed by k_cv1,
  // read by k_cv2, overwritten by k_cv3).
  unsigned short* zrow = (unsigned short*)d_out;

  k_cv1<<<2048, 256, 0, stream>>>(feat, W1, g1, b1, m1, v1, h, zrow);
  k_cv2<<<1024, 512, 0, stream>>>(h, nbr, W2, g2, b2, m2, v2, t, zrow);
  k_cv3<<<2048, 256, 0, stream>>>(t, W3, feat, g3, b3, m3, v3, (void*)d_out);
}

// Round 3
// 959.194 us; speedup vs baseline: 1.0685x; 1.0685x over previous
//
#include <hip/hip_runtime.h>

#define DEVINL __device__ __forceinline__

constexpr int N_SITES = 500000;
constexpr int C1 = 128;
constexpr int CH = 64;
constexpr int C2 = 128;
constexpr float BN_EPS = 1e-5f;
constexpr int NT32 = N_SITES / 32;   // 15625 tiles of 32 sites (exact)

typedef __attribute__((ext_vector_type(4))) float f32x4;
typedef __attribute__((ext_vector_type(8))) short s16x8;

DEVINL float bf2f(unsigned short s) { return __uint_as_float(((unsigned)s) << 16); }
DEVINL unsigned short f2bf(float f) {
  unsigned u = __float_as_uint(f);
  return (unsigned short)((u + 0x7fffu + ((u >> 16) & 1u)) >> 16);  // RNE
}
DEVINL float silu_f(float x) { return x / (1.0f + __expf(-x)); }

template<bool F32>
DEVINL float rdf(const void* p, long i) {
  if constexpr (F32) return ((const float*)p)[i];
  else return bf2f(((const unsigned short*)p)[i]);
}

DEVINL bool probe_f32(const void* buf) {
  unsigned w = ((const unsigned*)buf)[threadIdx.x & 63];
  unsigned e = (w >> 7) & 0xFFu;
  bool bf_like = (e >= 90u && e <= 134u) || ((w & 0xFFFFu) == 0u);
  return __popcll(__ballot(bf_like)) < 48;
}
DEVINL bool probe_i64(const int* nbr) {
  int v = nbr[2 * (threadIdx.x & 63) + 1];
  return __popcll(__ballot(v == 0)) == 64;
}
template<bool I64>
DEVINL int rd_idx(const int* nbr, long ofs) {
  if constexpr (I64) return nbr[2 * ofs];
  else return nbr[ofs];
}

DEVINL s16x8 as_s16x8(uint4 v) { union { uint4 u; s16x8 s; } c; c.u = v; return c.s; }

DEVINL s16x8 pack8(float a0, float a1, float a2, float a3,
                   float a4, float a5, float a6, float a7) {
  uint4 r;
  r.x = (unsigned)f2bf(a0) | ((unsigned)f2bf(a1) << 16);
  r.y = (unsigned)f2bf(a2) | ((unsigned)f2bf(a3) << 16);
  r.z = (unsigned)f2bf(a4) | ((unsigned)f2bf(a5) << 16);
  r.w = (unsigned)f2bf(a6) | ((unsigned)f2bf(a7) << 16);
  return as_s16x8(r);
}

// Swapped-operand MFMA: D = A*B, A = W^T (m = out-channel), B = data^T
// (n = site).  D layout: lane (lg*16+lr) holds site lr, channels lg*4+q
// within each 16-wide m-tile.
DEVINL f32x4 mfma16(s16x8 a, s16x8 b, f32x4 c) {
  return __builtin_amdgcn_mfma_f32_16x16x32_bf16(a, b, c, 0, 0, 0);
}

// Weight fragment packing: element (k, n) of a [K][M] slab -> frag
// (kk = k>>5, mt = n>>4), lane = ((k>>3)&3)*16 + (n&15), j = k&7.
// One frag = 64 lanes x 8 bf16 = 1KB, one ds_read_b128 per lane.

// ---------------------------------------------------------------------------
// K1: h = silu(bn1(features @ W1)), h bf16 [N][64] ROW-MAJOR (gather target).
// Epilogue bounces D-frags through LDS so global stores are line-contiguous
// (1KB per instr) -- avoids the ~8x sub-line write amplification.
// ---------------------------------------------------------------------------
template<bool F32>
DEVINL void cv1_body(const void* feat, const void* W1,
                     const void* g1, const void* b1, const void* m1, const void* v1,
                     unsigned short* __restrict__ h,
                     unsigned short* lw1, float* lsc, float* ltb,
                     unsigned short* sb /* [4 waves][16 rows][72] */)
{
  const int tid = threadIdx.x;
  for (int n = tid; n < CH; n += 256) {
    float s = rdf<F32>(g1, n) * rsqrtf(rdf<F32>(v1, n) + BN_EPS);
    lsc[n] = s;
    ltb[n] = rdf<F32>(b1, n) - rdf<F32>(m1, n) * s;
  }
  __syncthreads();
  for (int idx = tid; idx < C1 * CH; idx += 256) {
    int k = idx >> 6, n = idx & 63;
    int frag = (k >> 5) * 4 + (n >> 4);
    int ln = (((k >> 3) & 3) << 4) | (n & 15);
    lw1[(frag * 64 + ln) * 8 + (k & 7)] = f2bf(rdf<F32>(W1, idx) * lsc[n]);
  }
  __syncthreads();

  const int lane = tid & 63, w = tid >> 6;
  const int lr = lane & 15, lg = lane >> 4;
  const s16x8* lw1s = (const s16x8*)lw1;
  unsigned short* sw = sb + w * (16 * 72);
  s16x8 aw[4][4];
#pragma unroll
  for (int kk = 0; kk < 4; ++kk)
#pragma unroll
    for (int mt = 0; mt < 4; ++mt)
      aw[kk][mt] = lw1s[(kk * 4 + mt) * 64 + lane];

  const int stride = gridDim.x * 4;
  for (int tile = blockIdx.x * 4 + w; tile < NT32; tile += stride) {
    const long base = (long)tile * 32;
    f32x4 acc[2][4];
#pragma unroll
    for (int st = 0; st < 2; ++st)
#pragma unroll
      for (int mt = 0; mt < 4; ++mt) acc[st][mt] = (f32x4)0.0f;

#pragma unroll
    for (int st = 0; st < 2; ++st) {
      const long row = base + st * 16 + lr;
#pragma unroll
      for (int kk = 0; kk < 4; ++kk) {
        s16x8 b;
        if constexpr (F32) {
          const float* fp = (const float*)feat + row * C1 + kk * 32 + lg * 8;
          float4 f0 = ((const float4*)fp)[0];
          float4 f1 = ((const float4*)fp)[1];
          b = pack8(f0.x, f0.y, f0.z, f0.w, f1.x, f1.y, f1.z, f1.w);
        } else {
          b = as_s16x8(*(const uint4*)((const unsigned short*)feat + row * C1 + kk * 32 + lg * 8));
        }
#pragma unroll
        for (int mt = 0; mt < 4; ++mt)
          acc[st][mt] = mfma16(aw[kk][mt], b, acc[st][mt]);
      }
    }
    // Epilogue: BN + SiLU, LDS bounce, contiguous 1KB stores.
#pragma unroll
    for (int st = 0; st < 2; ++st) {
      __builtin_amdgcn_wave_barrier();
#pragma unroll
      for (int mt = 0; mt < 4; ++mt) {
        int ch4 = mt * 16 + lg * 4;
        f32x4 tb = *(const f32x4*)&ltb[ch4];
        f32x4 v = acc[st][mt];
        ushort4 hv;
        hv.x = f2bf(silu_f(v[0] + tb[0]));
        hv.y = f2bf(silu_f(v[1] + tb[1]));
        hv.z = f2bf(silu_f(v[2] + tb[2]));
        hv.w = f2bf(silu_f(v[3] + tb[3]));
        *(ushort4*)(sw + lr * 72 + ch4) = hv;   // padded stride 72 (bank spread)
      }
      __builtin_amdgcn_wave_barrier();
      uint4 r1 = *(const uint4*)(sw + (lane >> 3) * 72 + (lane & 7) * 8);
      uint4 r2 = *(const uint4*)(sw + (8 + (lane >> 3)) * 72 + (lane & 7) * 8);
      size_t ho = (size_t)(base + st * 16) * CH;
      *(uint4*)(h + ho + lane * 8) = r1;          // 1KB contiguous per instr
      *(uint4*)(h + ho + 512 + lane * 8) = r2;
      __builtin_amdgcn_wave_barrier();
    }
  }
}

__global__ __launch_bounds__(256, 4) void k_cv1(
    const void* feat, const void* W1,
    const void* g1, const void* b1, const void* m1, const void* v1,
    unsigned short* __restrict__ h, unsigned short* __restrict__ zrow)
{
  __shared__ __align__(16) unsigned short lw1[16 * 64 * 8];   // 16 KiB
  __shared__ __align__(16) unsigned short sb[4 * 16 * 72];    // 9.2 KiB
  __shared__ __align__(16) float lsc[CH];
  __shared__ __align__(16) float ltb[CH];
  if (blockIdx.x == 0 && threadIdx.x < 8)
    ((uint4*)zrow)[threadIdx.x] = make_uint4(0u, 0u, 0u, 0u);
  if (probe_f32(feat)) cv1_body<true >(feat, W1, g1, b1, m1, v1, h, lw1, lsc, ltb, sb);
  else                 cv1_body<false>(feat, W1, g1, b1, m1, v1, h, lw1, lsc, ltb, sb);
}

// ---------------------------------------------------------------------------
// K2: t = silu(bn2( sum_{k=0..8} gather(h, nbr[k]) @ W2[k] )).
// t is stored in FRAGMENT-BLOCKED layout [tile][st][kk][lane] (16B units):
// cv2's per-(st,mt) ushort4 store covers a contiguous 512B run, and cv3's
// B-fragment load is a contiguous uint4 at lane*16.  Gathers are software-
// pipelined 3 taps deep with all index loads hoisted.
// ---------------------------------------------------------------------------
#define CV2_ISSUE(slot, tap_) do {                                              \
    const unsigned short* s0_ = (i0[tap_] == N_SITES) ? zrow                     \
                                : h + (size_t)i0[tap_] * CH;                     \
    const unsigned short* s1_ = (i1[tap_] == N_SITES) ? zrow                     \
                                : h + (size_t)i1[tap_] * CH;                     \
    G[slot][0] = as_s16x8(*(const uint4*)(s0_ + lg * 8));                        \
    G[slot][1] = as_s16x8(*(const uint4*)(s0_ + 32 + lg * 8));                   \
    G[slot][2] = as_s16x8(*(const uint4*)(s1_ + lg * 8));                        \
    G[slot][3] = as_s16x8(*(const uint4*)(s1_ + 32 + lg * 8));                   \
  } while (0)

template<bool F32, bool I64>
DEVINL void cv2_body(const unsigned short* __restrict__ h, const int* __restrict__ nbr,
                     const void* W2,
                     const void* g2, const void* b2, const void* m2, const void* v2,
                     unsigned short* __restrict__ t,
                     const unsigned short* __restrict__ zrow,
                     unsigned short* lw2, float* lsc, float* ltb)
{
  const int tid = threadIdx.x;
  for (int n = tid; n < CH; n += 512) {
    float s = rdf<F32>(g2, n) * rsqrtf(rdf<F32>(v2, n) + BN_EPS);
    lsc[n] = s;
    ltb[n] = rdf<F32>(b2, n) - rdf<F32>(m2, n) * s;
  }
  __syncthreads();
  for (int idx = tid; idx < 9 * CH * CH; idx += 512) {
    int tap = idx >> 12;
    int k = (idx >> 6) & 63, n = idx & 63;
    int frag = (tap * 2 + (k >> 5)) * 4 + (n >> 4);
    int ln = (((k >> 3) & 3) << 4) | (n & 15);
    lw2[(frag * 64 + ln) * 8 + (k & 7)] = f2bf(rdf<F32>(W2, (long)idx) * lsc[n]);
  }
  __syncthreads();

  const int lane = tid & 63, w = tid >> 6;   // w in [0,8)
  const int lr = lane & 15, lg = lane >> 4;
  const s16x8* lw2s = (const s16x8*)lw2;

  const int stride = gridDim.x * 8;
  for (int tile = blockIdx.x * 8 + w; tile < NT32; tile += stride) {
    const long base = (long)tile * 32;
    int i0[9], i1[9];
#pragma unroll
    for (int tap = 0; tap < 9; ++tap) {
      i0[tap] = rd_idx<I64>(nbr, (long)tap * N_SITES + base + lr);
      i1[tap] = rd_idx<I64>(nbr, (long)tap * N_SITES + base + 16 + lr);
    }
    f32x4 acc[2][4];
#pragma unroll
    for (int st = 0; st < 2; ++st)
#pragma unroll
      for (int mt = 0; mt < 4; ++mt) acc[st][mt] = (f32x4)0.0f;

    s16x8 G[3][4];
    CV2_ISSUE(0, 0); CV2_ISSUE(1, 1); CV2_ISSUE(2, 2);
#pragma unroll
    for (int tap = 0; tap < 9; ++tap) {
      const int slot = tap % 3;   // compile-time after unroll
#pragma unroll
      for (int mt = 0; mt < 4; ++mt) {
        s16x8 a0 = lw2s[((tap * 2 + 0) * 4 + mt) * 64 + lane];
        s16x8 a1 = lw2s[((tap * 2 + 1) * 4 + mt) * 64 + lane];
        acc[0][mt] = mfma16(a0, G[slot][0], acc[0][mt]);
        acc[0][mt] = mfma16(a1, G[slot][1], acc[0][mt]);
        acc[1][mt] = mfma16(a0, G[slot][2], acc[1][mt]);
        acc[1][mt] = mfma16(a1, G[slot][3], acc[1][mt]);
      }
      if (tap + 3 < 9) CV2_ISSUE(slot, tap + 3);
    }
    // Store into fragment-blocked t: contiguous 512B per instruction.
    unsigned short* tb = t + (size_t)tile * 2048;
#pragma unroll
    for (int st = 0; st < 2; ++st)
#pragma unroll
      for (int mt = 0; mt < 4; ++mt) {
        int ch4 = mt * 16 + lg * 4;
        f32x4 tbv = *(const f32x4*)&ltb[ch4];
        f32x4 v = acc[st][mt];
        ushort4 tv;
        tv.x = f2bf(silu_f(v[0] + tbv[0]));
        tv.y = f2bf(silu_f(v[1] + tbv[1]));
        tv.z = f2bf(silu_f(v[2] + tbv[2]));
        tv.w = f2bf(silu_f(v[3] + tbv[3]));
        int ofs = st * 1024 + (mt >> 1) * 512 + (((mt & 1) * 2) + (lg >> 1)) * 128
                + lr * 8 + (lg & 1) * 4;
        *(ushort4*)(tb + ofs) = tv;
      }
  }
}

__global__ __launch_bounds__(512, 3) void k_cv2(
    const unsigned short* __restrict__ h, const int* __restrict__ nbr,
    const void* W2,
    const void* g2, const void* b2, const void* m2, const void* v2,
    unsigned short* __restrict__ t, const unsigned short* __restrict__ zrow)
{
  __shared__ __align__(16) unsigned short lw2[72 * 64 * 8];  // 73728 B
  __shared__ __align__(16) float lsc[CH];
  __shared__ __align__(16) float ltb[CH];
  bool f32 = probe_f32(W2);
  bool i64 = probe_i64(nbr);
  if (f32) { if (i64) cv2_body<true , true >(h, nbr, W2, g2, b2, m2, v2, t, zrow, lw2, lsc, ltb);
             else     cv2_body<true , false>(h, nbr, W2, g2, b2, m2, v2, t, zrow, lw2, lsc, ltb); }
  else     { if (i64) cv2_body<false, true >(h, nbr, W2, g2, b2, m2, v2, t, zrow, lw2, lsc, ltb);
             else     cv2_body<false, false>(h, nbr, W2, g2, b2, m2, v2, t, zrow, lw2, lsc, ltb); }
}

// ---------------------------------------------------------------------------
// K3: out = silu( bn3(t @ W3) + features ).  t read in fragment-blocked
// layout (contiguous 1KB loads).  F32 epilogue: 64B-chunk stores per row.
// ---------------------------------------------------------------------------
template<bool F32>
DEVINL void cv3_body(const unsigned short* __restrict__ t, const void* W3,
                     const void* feat,
                     const void* g3, const void* b3, const void* m3, const void* v3,
                     void* out, unsigned short* lw3, float* lsc, float* ltb)
{
  const int tid = threadIdx.x;
  for (int n = tid; n < C2; n += 256) {
    float s = rdf<F32>(g3, n) * rsqrtf(rdf<F32>(v3, n) + BN_EPS);
    lsc[n] = s;
    ltb[n] = rdf<F32>(b3, n) - rdf<F32>(m3, n) * s;
  }
  __syncthreads();
  for (int idx = tid; idx < CH * C2; idx += 256) {
    int k = idx >> 7, n = idx & 127;
    int frag = (k >> 5) * 8 + (n >> 4);
    int ln = (((k >> 3) & 3) << 4) | (n & 15);
    lw3[(frag * 64 + ln) * 8 + (k & 7)] = f2bf(rdf<F32>(W3, (long)idx) * lsc[n]);
  }
  __syncthreads();

  const int lane = tid & 63, w = tid >> 6;
  const int lr = lane & 15, lg = lane >> 4;
  const s16x8* lw3s = (const s16x8*)lw3;

  const int stride = gridDim.x * 4;
  for (int tile = blockIdx.x * 4 + w; tile < NT32; tile += stride) {
    const long base = (long)tile * 32;
    const unsigned short* tb = t + (size_t)tile * 2048;
    s16x8 bfr[2][2];
#pragma unroll
    for (int st = 0; st < 2; ++st) {
      bfr[st][0] = as_s16x8(*(const uint4*)(tb + st * 1024 + lane * 8));
      bfr[st][1] = as_s16x8(*(const uint4*)(tb + st * 1024 + 512 + lane * 8));
    }
#pragma unroll
    for (int half = 0; half < 2; ++half) {
      s16x8 a[2][4];
#pragma unroll
      for (int kk = 0; kk < 2; ++kk)
#pragma unroll
        for (int m = 0; m < 4; ++m)
          a[kk][m] = lw3s[(kk * 8 + half * 4 + m) * 64 + lane];
      f32x4 acc[2][4];
#pragma unroll
      for (int st = 0; st < 2; ++st)
#pragma unroll
        for (int m = 0; m < 4; ++m) acc[st][m] = (f32x4)0.0f;
#pragma unroll
      for (int st = 0; st < 2; ++st)
#pragma unroll
        for (int kk = 0; kk < 2; ++kk)
#pragma unroll
          for (int m = 0; m < 4; ++m)
            acc[st][m] = mfma16(a[kk][m], bfr[st][kk], acc[st][m]);
#pragma unroll
      for (int st = 0; st < 2; ++st) {
        const size_t site = (size_t)(base + st * 16 + lr);
#pragma unroll
        for (int m = 0; m < 4; ++m) {
          int ch4 = (half * 4 + m) * 16 + lg * 4;
          f32x4 tbv = *(const f32x4*)&ltb[ch4];
          f32x4 v = acc[st][m];
          float f0, f1, f2v, f3;
          if constexpr (F32) {
            float4 fv = *(const float4*)((const float*)feat + site * C1 + ch4);
            f0 = fv.x; f1 = fv.y; f2v = fv.z; f3 = fv.w;
          } else {
            const unsigned short* fp = (const unsigned short*)feat + site * C1 + ch4;
            ushort4 fu = *(const ushort4*)fp;
            f0 = bf2f(fu.x); f1 = bf2f(fu.y); f2v = bf2f(fu.z); f3 = bf2f(fu.w);
          }
          float r0 = silu_f(v[0] + tbv[0] + f0);
          float r1 = silu_f(v[1] + tbv[1] + f1);
          float r2 = silu_f(v[2] + tbv[2] + f2v);
          float r3 = silu_f(v[3] + tbv[3] + f3);
          if constexpr (F32) {
            float4 ov; ov.x = r0; ov.y = r1; ov.z = r2; ov.w = r3;
            *(float4*)((float*)out + site * C2 + ch4) = ov;
          } else {
            ushort4 ov;
            ov.x = f2bf(r0); ov.y = f2bf(r1); ov.z = f2bf(r2); ov.w = f2bf(r3);
            *(ushort4*)((unsigned short*)out + site * C2 + ch4) = ov;
          }
        }
      }
    }
  }
}

__global__ __launch_bounds__(256, 4) void k_cv3(
    const unsigned short* __restrict__ t, const void* W3, const void* feat,
    const void* g3, const void* b3, const void* m3, const void* v3,
    void* out)
{
  __shared__ __align__(16) unsigned short lw3[16 * 64 * 8];  // 16 KiB
  __shared__ __align__(16) float lsc[C2];
  __shared__ __align__(16) float ltb[C2];
  if (probe_f32(feat)) cv3_body<true >(t, W3, feat, g3, b3, m3, v3, out, lw3, lsc, ltb);
  else                 cv3_body<false>(t, W3, feat, g3, b3, m3, v3, out, lw3, lsc, ltb);
}

// ---------------------------------------------------------------------------
extern "C" void kernel_launch(void* const* d_in, const int* in_sizes, int n_in,
                              void* d_out, int out_size, void* d_ws, size_t ws_size,
                              hipStream_t stream)
{
  (void)out_size; (void)ws_size;
  // dict order: feat(64e6B) nbr W1 W2 W3 g1 b1 m1 v1 g2 b2 m2 v2 g3 b3 m3 v3
  int mp[17];
  for (int i = 0; i < 17; ++i) mp[i] = i;
  if (n_in == 17 && in_sizes[0] != 64000000 &&
      in_sizes[6] == 64000000 && in_sizes[13] == 4500000) {
    const int amap[17] = {6, 13, 0, 1, 2, 7, 3, 10, 14, 8, 4, 11, 15, 9, 5, 12, 16};
    for (int i = 0; i < 17; ++i) mp[i] = amap[i];
  }
  const void* feat = d_in[mp[0]];
  const int*  nbr  = (const int*)d_in[mp[1]];
  const void* W1 = d_in[mp[2]];
  const void* W2 = d_in[mp[3]];
  const void* W3 = d_in[mp[4]];
  const void* g1 = d_in[mp[5]],  *b1 = d_in[mp[6]],  *m1 = d_in[mp[7]],  *v1 = d_in[mp[8]];
  const void* g2 = d_in[mp[9]],  *b2 = d_in[mp[10]], *m2 = d_in[mp[11]], *v2 = d_in[mp[12]];
  const void* g3 = d_in[mp[13]], *b3 = d_in[mp[14]], *m3 = d_in[mp[15]], *v3 = d_in[mp[16]];

  // workspace: h = N*64 bf16 row-major; t = N*64 bf16 fragment-blocked
  unsigned short* h = (unsigned short*)d_ws;
  unsigned short* t = (unsigned short*)((char*)d_ws + (size_t)N_SITES * CH * 2);
  // 128B zero row for sentinel gathers at start of d_out (zeroed by k_cv1,
  // read by k_cv2, overwritten by k_cv3).
  unsigned short* zrow = (unsigned short*)d_out;

  k_cv1<<<2048, 256, 0, stream>>>(feat, W1, g1, b1, m1, v1, h, zrow);
  k_cv2<<<1024, 512, 0, stream>>>(h, nbr, W2, g2, b2, m2, v2, t, zrow);
  k_cv3<<<2048, 256, 0, stream>>>(t, W3, feat, g3, b3, m3, v3, (void*)d_out);
}

// Round 4
// 922.986 us; speedup vs baseline: 1.1104x; 1.0392x over previous
//
#include <hip/hip_runtime.h>

#define DEVINL __device__ __forceinline__

constexpr int N_SITES = 500000;
constexpr int C1 = 128;
constexpr int CH = 64;
constexpr int C2 = 128;
constexpr float BN_EPS = 1e-5f;
constexpr int NT32 = N_SITES / 32;   // 15625 tiles of 32 sites (exact)

typedef __attribute__((ext_vector_type(4))) float f32x4;
typedef __attribute__((ext_vector_type(8))) short s16x8;

DEVINL float bf2f(unsigned short s) { return __uint_as_float(((unsigned)s) << 16); }
DEVINL unsigned short f2bf(float f) {
  unsigned u = __float_as_uint(f);
  return (unsigned short)((u + 0x7fffu + ((u >> 16) & 1u)) >> 16);  // RNE
}
DEVINL float silu_f(float x) { return x / (1.0f + __expf(-x)); }

template<bool F32>
DEVINL float rdf(const void* p, long i) {
  if constexpr (F32) return ((const float*)p)[i];
  else return bf2f(((const unsigned short*)p)[i]);
}

DEVINL bool probe_f32(const void* buf) {
  unsigned w = ((const unsigned*)buf)[threadIdx.x & 63];
  unsigned e = (w >> 7) & 0xFFu;
  bool bf_like = (e >= 90u && e <= 134u) || ((w & 0xFFFFu) == 0u);
  return __popcll(__ballot(bf_like)) < 48;
}
DEVINL bool probe_i64(const int* nbr) {
  int v = nbr[2 * (threadIdx.x & 63) + 1];
  return __popcll(__ballot(v == 0)) == 64;
}
template<bool I64>
DEVINL int rd_idx(const int* nbr, long ofs) {
  if constexpr (I64) return nbr[2 * ofs];
  else return nbr[ofs];
}

DEVINL s16x8 as_s16x8(uint4 v) { union { uint4 u; s16x8 s; } c; c.u = v; return c.s; }

DEVINL s16x8 pack8(float a0, float a1, float a2, float a3,
                   float a4, float a5, float a6, float a7) {
  uint4 r;
  r.x = (unsigned)f2bf(a0) | ((unsigned)f2bf(a1) << 16);
  r.y = (unsigned)f2bf(a2) | ((unsigned)f2bf(a3) << 16);
  r.z = (unsigned)f2bf(a4) | ((unsigned)f2bf(a5) << 16);
  r.w = (unsigned)f2bf(a6) | ((unsigned)f2bf(a7) << 16);
  return as_s16x8(r);
}

// Swapped-operand MFMA: D = A*B, A = W^T (m = out-channel), B = data^T
// (n = site).  D layout: lane (lg*16+lr) holds site lr, channels lg*4+q
// within each 16-wide m-tile.
DEVINL f32x4 mfma16(s16x8 a, s16x8 b, f32x4 c) {
  return __builtin_amdgcn_mfma_f32_16x16x32_bf16(a, b, c, 0, 0, 0);
}

// Weight fragment packing: element (k, n) of a [K][M] slab -> frag
// (kk = k>>5, mt = n>>4), lane = ((k>>3)&3)*16 + (n&15), j = k&7.
// One frag = 64 lanes x 8 bf16 = 1KB, one ds_read_b128 per lane.

// ---------------------------------------------------------------------------
// K1: h = silu(bn1(features @ W1)), h bf16 [N][64] ROW-MAJOR (gather target).
// Epilogue bounces D-frags through LDS so global stores are LANE-ASCENDING
// 16B/lane (1KB contiguous per instruction).
// ---------------------------------------------------------------------------
template<bool F32>
DEVINL void cv1_body(const void* feat, const void* W1,
                     const void* g1, const void* b1, const void* m1, const void* v1,
                     unsigned short* __restrict__ h,
                     unsigned short* lw1, float* lsc, float* ltb,
                     unsigned short* sb /* [4 waves][16 rows][72] */)
{
  const int tid = threadIdx.x;
  for (int n = tid; n < CH; n += 256) {
    float s = rdf<F32>(g1, n) * rsqrtf(rdf<F32>(v1, n) + BN_EPS);
    lsc[n] = s;
    ltb[n] = rdf<F32>(b1, n) - rdf<F32>(m1, n) * s;
  }
  __syncthreads();
  for (int idx = tid; idx < C1 * CH; idx += 256) {
    int k = idx >> 6, n = idx & 63;
    int frag = (k >> 5) * 4 + (n >> 4);
    int ln = (((k >> 3) & 3) << 4) | (n & 15);
    lw1[(frag * 64 + ln) * 8 + (k & 7)] = f2bf(rdf<F32>(W1, idx) * lsc[n]);
  }
  __syncthreads();

  const int lane = tid & 63, w = tid >> 6;
  const int lr = lane & 15, lg = lane >> 4;
  const s16x8* lw1s = (const s16x8*)lw1;
  unsigned short* sw = sb + w * (16 * 72);
  s16x8 aw[4][4];
#pragma unroll
  for (int kk = 0; kk < 4; ++kk)
#pragma unroll
    for (int mt = 0; mt < 4; ++mt)
      aw[kk][mt] = lw1s[(kk * 4 + mt) * 64 + lane];

  const int stride = gridDim.x * 4;
  for (int tile = blockIdx.x * 4 + w; tile < NT32; tile += stride) {
    const long base = (long)tile * 32;
    f32x4 acc[2][4];
#pragma unroll
    for (int st = 0; st < 2; ++st)
#pragma unroll
      for (int mt = 0; mt < 4; ++mt) acc[st][mt] = (f32x4)0.0f;

#pragma unroll
    for (int st = 0; st < 2; ++st) {
      const long row = base + st * 16 + lr;
#pragma unroll
      for (int kk = 0; kk < 4; ++kk) {
        s16x8 b;
        if constexpr (F32) {
          const float* fp = (const float*)feat + row * C1 + kk * 32 + lg * 8;
          float4 f0 = ((const float4*)fp)[0];
          float4 f1 = ((const float4*)fp)[1];
          b = pack8(f0.x, f0.y, f0.z, f0.w, f1.x, f1.y, f1.z, f1.w);
        } else {
          b = as_s16x8(*(const uint4*)((const unsigned short*)feat + row * C1 + kk * 32 + lg * 8));
        }
#pragma unroll
        for (int mt = 0; mt < 4; ++mt)
          acc[st][mt] = mfma16(aw[kk][mt], b, acc[st][mt]);
      }
    }
    // Epilogue: BN + SiLU, LDS bounce, lane-ascending 1KB stores.
#pragma unroll
    for (int st = 0; st < 2; ++st) {
      __builtin_amdgcn_wave_barrier();
#pragma unroll
      for (int mt = 0; mt < 4; ++mt) {
        int ch4 = mt * 16 + lg * 4;
        f32x4 tb = *(const f32x4*)&ltb[ch4];
        f32x4 v = acc[st][mt];
        ushort4 hv;
        hv.x = f2bf(silu_f(v[0] + tb[0]));
        hv.y = f2bf(silu_f(v[1] + tb[1]));
        hv.z = f2bf(silu_f(v[2] + tb[2]));
        hv.w = f2bf(silu_f(v[3] + tb[3]));
        *(ushort4*)(sw + lr * 72 + ch4) = hv;   // padded stride 72 (bank spread)
      }
      __builtin_amdgcn_wave_barrier();
      uint4 r1 = *(const uint4*)(sw + (lane >> 3) * 72 + (lane & 7) * 8);
      uint4 r2 = *(const uint4*)(sw + (8 + (lane >> 3)) * 72 + (lane & 7) * 8);
      size_t ho = (size_t)(base + st * 16) * CH;
      *(uint4*)(h + ho + lane * 8) = r1;          // 1KB ascending per instr
      *(uint4*)(h + ho + 512 + lane * 8) = r2;
      __builtin_amdgcn_wave_barrier();
    }
  }
}

__global__ __launch_bounds__(256, 4) void k_cv1(
    const void* feat, const void* W1,
    const void* g1, const void* b1, const void* m1, const void* v1,
    unsigned short* __restrict__ h, unsigned short* __restrict__ zrow)
{
  __shared__ __align__(16) unsigned short lw1[16 * 64 * 8];   // 16 KiB
  __shared__ __align__(16) unsigned short sb[4 * 16 * 72];    // 9.2 KiB
  __shared__ __align__(16) float lsc[CH];
  __shared__ __align__(16) float ltb[CH];
  if (blockIdx.x == 0 && threadIdx.x < 8)
    ((uint4*)zrow)[threadIdx.x] = make_uint4(0u, 0u, 0u, 0u);
  if (probe_f32(feat)) cv1_body<true >(feat, W1, g1, b1, m1, v1, h, lw1, lsc, ltb, sb);
  else                 cv1_body<false>(feat, W1, g1, b1, m1, v1, h, lw1, lsc, ltb, sb);
}

// ---------------------------------------------------------------------------
// K2: t = silu(bn2( sum_{k=0..8} gather(h, nbr[k]) @ W2[k] )).
// t stored in D-NATURAL layout: t[tile][st][mt][lane][q] (q = 4 bf16).
// Store address = tb + st*1024 + mt*256 + lane*4 -> MONOTONIC IN LANE,
// 512B ascending per instruction => full write coalescing.
// ---------------------------------------------------------------------------
#define CV2_ISSUE(slot, tap_) do {                                              \
    const unsigned short* s0_ = (i0[tap_] == N_SITES) ? zrow                     \
                                : h + (size_t)i0[tap_] * CH;                     \
    const unsigned short* s1_ = (i1[tap_] == N_SITES) ? zrow                     \
                                : h + (size_t)i1[tap_] * CH;                     \
    G[slot][0] = as_s16x8(*(const uint4*)(s0_ + lg * 8));                        \
    G[slot][1] = as_s16x8(*(const uint4*)(s0_ + 32 + lg * 8));                   \
    G[slot][2] = as_s16x8(*(const uint4*)(s1_ + lg * 8));                        \
    G[slot][3] = as_s16x8(*(const uint4*)(s1_ + 32 + lg * 8));                   \
  } while (0)

template<bool F32, bool I64>
DEVINL void cv2_body(const unsigned short* __restrict__ h, const int* __restrict__ nbr,
                     const void* W2,
                     const void* g2, const void* b2, const void* m2, const void* v2,
                     unsigned short* __restrict__ t,
                     const unsigned short* __restrict__ zrow,
                     unsigned short* lw2, float* lsc, float* ltb)
{
  const int tid = threadIdx.x;
  for (int n = tid; n < CH; n += 512) {
    float s = rdf<F32>(g2, n) * rsqrtf(rdf<F32>(v2, n) + BN_EPS);
    lsc[n] = s;
    ltb[n] = rdf<F32>(b2, n) - rdf<F32>(m2, n) * s;
  }
  __syncthreads();
  for (int idx = tid; idx < 9 * CH * CH; idx += 512) {
    int tap = idx >> 12;
    int k = (idx >> 6) & 63, n = idx & 63;
    int frag = (tap * 2 + (k >> 5)) * 4 + (n >> 4);
    int ln = (((k >> 3) & 3) << 4) | (n & 15);
    lw2[(frag * 64 + ln) * 8 + (k & 7)] = f2bf(rdf<F32>(W2, (long)idx) * lsc[n]);
  }
  __syncthreads();

  const int lane = tid & 63, w = tid >> 6;   // w in [0,8)
  const int lr = lane & 15, lg = lane >> 4;
  const s16x8* lw2s = (const s16x8*)lw2;

  const int stride = gridDim.x * 8;
  for (int tile = blockIdx.x * 8 + w; tile < NT32; tile += stride) {
    const long base = (long)tile * 32;
    int i0[9], i1[9];
#pragma unroll
    for (int tap = 0; tap < 9; ++tap) {
      i0[tap] = rd_idx<I64>(nbr, (long)tap * N_SITES + base + lr);
      i1[tap] = rd_idx<I64>(nbr, (long)tap * N_SITES + base + 16 + lr);
    }
    f32x4 acc[2][4];
#pragma unroll
    for (int st = 0; st < 2; ++st)
#pragma unroll
      for (int mt = 0; mt < 4; ++mt) acc[st][mt] = (f32x4)0.0f;

    s16x8 G[3][4];
    CV2_ISSUE(0, 0); CV2_ISSUE(1, 1); CV2_ISSUE(2, 2);
#pragma unroll
    for (int tap = 0; tap < 9; ++tap) {
      const int slot = tap % 3;   // compile-time after unroll
#pragma unroll
      for (int mt = 0; mt < 4; ++mt) {
        s16x8 a0 = lw2s[((tap * 2 + 0) * 4 + mt) * 64 + lane];
        s16x8 a1 = lw2s[((tap * 2 + 1) * 4 + mt) * 64 + lane];
        acc[0][mt] = mfma16(a0, G[slot][0], acc[0][mt]);
        acc[0][mt] = mfma16(a1, G[slot][1], acc[0][mt]);
        acc[1][mt] = mfma16(a0, G[slot][2], acc[1][mt]);
        acc[1][mt] = mfma16(a1, G[slot][3], acc[1][mt]);
      }
      if (tap + 3 < 9) CV2_ISSUE(slot, tap + 3);
    }
    // Store D-natural: lane-ascending 8B/lane, 512B contiguous per instr.
    unsigned short* tb = t + (size_t)tile * 2048;
#pragma unroll
    for (int st = 0; st < 2; ++st)
#pragma unroll
      for (int mt = 0; mt < 4; ++mt) {
        int ch4 = mt * 16 + lg * 4;
        f32x4 tbv = *(const f32x4*)&ltb[ch4];
        f32x4 v = acc[st][mt];
        ushort4 tv;
        tv.x = f2bf(silu_f(v[0] + tbv[0]));
        tv.y = f2bf(silu_f(v[1] + tbv[1]));
        tv.z = f2bf(silu_f(v[2] + tbv[2]));
        tv.w = f2bf(silu_f(v[3] + tbv[3]));
        *(ushort4*)(tb + st * 1024 + mt * 256 + lane * 4) = tv;
      }
  }
}

__global__ __launch_bounds__(512, 3) void k_cv2(
    const unsigned short* __restrict__ h, const int* __restrict__ nbr,
    const void* W2,
    const void* g2, const void* b2, const void* m2, const void* v2,
    unsigned short* __restrict__ t, const unsigned short* __restrict__ zrow)
{
  __shared__ __align__(16) unsigned short lw2[72 * 64 * 8];  // 73728 B
  __shared__ __align__(16) float lsc[CH];
  __shared__ __align__(16) float ltb[CH];
  bool f32 = probe_f32(W2);
  bool i64 = probe_i64(nbr);
  if (f32) { if (i64) cv2_body<true , true >(h, nbr, W2, g2, b2, m2, v2, t, zrow, lw2, lsc, ltb);
             else     cv2_body<true , false>(h, nbr, W2, g2, b2, m2, v2, t, zrow, lw2, lsc, ltb); }
  else     { if (i64) cv2_body<false, true >(h, nbr, W2, g2, b2, m2, v2, t, zrow, lw2, lsc, ltb);
             else     cv2_body<false, false>(h, nbr, W2, g2, b2, m2, v2, t, zrow, lw2, lsc, ltb); }
}

// ---------------------------------------------------------------------------
// K3: out = silu( bn3(t @ W3) + features ).  t read from D-natural layout
// (two ushort4 per B-fragment).  Epilogue bounces through an XOR-swizzled
// LDS scratch so out-stores are lane-ascending float4 (1KB per instr).
// ---------------------------------------------------------------------------
template<bool F32>
DEVINL void cv3_body(const unsigned short* __restrict__ t, const void* W3,
                     const void* feat,
                     const void* g3, const void* b3, const void* m3, const void* v3,
                     void* out, unsigned short* lw3, float* lsc, float* ltb,
                     float* sb3)
{
  const int tid = threadIdx.x;
  for (int n = tid; n < C2; n += 256) {
    float s = rdf<F32>(g3, n) * rsqrtf(rdf<F32>(v3, n) + BN_EPS);
    lsc[n] = s;
    ltb[n] = rdf<F32>(b3, n) - rdf<F32>(m3, n) * s;
  }
  __syncthreads();
  for (int idx = tid; idx < CH * C2; idx += 256) {
    int k = idx >> 7, n = idx & 127;
    int frag = (k >> 5) * 8 + (n >> 4);
    int ln = (((k >> 3) & 3) << 4) | (n & 15);
    lw3[(frag * 64 + ln) * 8 + (k & 7)] = f2bf(rdf<F32>(W3, (long)idx) * lsc[n]);
  }
  __syncthreads();

  const int lane = tid & 63, w = tid >> 6;
  const int lr = lane & 15, lg = lane >> 4;
  const s16x8* lw3s = (const s16x8*)lw3;
  float* sw = sb3 + w * 2048;             // 16 rows x 128 f32 (chunk-swizzled)

  s16x8 aw[2][8];
#pragma unroll
  for (int kk = 0; kk < 2; ++kk)
#pragma unroll
    for (int mm = 0; mm < 8; ++mm)
      aw[kk][mm] = lw3s[(kk * 8 + mm) * 64 + lane];

  const int c4r = lane & 31;    // readback chunk index (4 floats)
  const int rpar = lane >> 5;   // readback row parity

  const int stride = gridDim.x * 4;
  for (int tile = blockIdx.x * 4 + w; tile < NT32; tile += stride) {
    const long base = (long)tile * 32;
    const unsigned short* tb = t + (size_t)tile * 2048;
#pragma unroll
    for (int st = 0; st < 2; ++st) {
      // B fragments from D-natural t: two ushort4 per fragment.
      s16x8 bfr[2];
#pragma unroll
      for (int kk = 0; kk < 2; ++kk) {
        int b0 = st * 1024 + (2 * kk + (lg >> 1)) * 256 + ((lg & 1) * 32 + lr) * 4;
        union { ushort4 u[2]; s16x8 s; } cc;
        cc.u[0] = *(const ushort4*)(tb + b0);
        cc.u[1] = *(const ushort4*)(tb + b0 + 64);
        bfr[kk] = cc.s;
      }
      f32x4 acc[8];
#pragma unroll
      for (int mm = 0; mm < 8; ++mm) acc[mm] = (f32x4)0.0f;
#pragma unroll
      for (int kk = 0; kk < 2; ++kk)
#pragma unroll
        for (int mm = 0; mm < 8; ++mm)
          acc[mm] = mfma16(aw[kk][mm], bfr[kk], acc[mm]);

      // D (+bias) -> swizzled LDS scratch.
      __builtin_amdgcn_wave_barrier();
#pragma unroll
      for (int mm = 0; mm < 8; ++mm) {
        int ch4 = mm * 16 + lg * 4;
        f32x4 tbv = *(const f32x4*)&ltb[ch4];
        f32x4 v = acc[mm] + tbv;
        int c4 = mm * 4 + lg;
        *(f32x4*)&sw[lr * 128 + (c4 ^ (lr & 7)) * 4] = v;
      }
      __builtin_amdgcn_wave_barrier();
      // Readback row-major: residual + SiLU + lane-ascending stores.
#pragma unroll
      for (int i = 0; i < 8; ++i) {
        int R = 2 * i + rpar;
        f32x4 o = *(const f32x4*)&sw[R * 128 + (c4r ^ (R & 7)) * 4];
        size_t site = (size_t)(base + st * 16 + R);
        if constexpr (F32) {
          float4 fv = *(const float4*)((const float*)feat + site * C1 + c4r * 4);
          float4 ov;
          ov.x = silu_f(o[0] + fv.x);
          ov.y = silu_f(o[1] + fv.y);
          ov.z = silu_f(o[2] + fv.z);
          ov.w = silu_f(o[3] + fv.w);
          *(float4*)((float*)out + site * C2 + c4r * 4) = ov;
        } else {
          const unsigned short* fp = (const unsigned short*)feat + site * C1 + c4r * 4;
          ushort4 fu = *(const ushort4*)fp;
          ushort4 ov;
          ov.x = f2bf(silu_f(o[0] + bf2f(fu.x)));
          ov.y = f2bf(silu_f(o[1] + bf2f(fu.y)));
          ov.z = f2bf(silu_f(o[2] + bf2f(fu.z)));
          ov.w = f2bf(silu_f(o[3] + bf2f(fu.w)));
          *(ushort4*)((unsigned short*)out + site * C2 + c4r * 4) = ov;
        }
      }
      __builtin_amdgcn_wave_barrier();
    }
  }
}

__global__ __launch_bounds__(256, 3) void k_cv3(
    const unsigned short* __restrict__ t, const void* W3, const void* feat,
    const void* g3, const void* b3, const void* m3, const void* v3,
    void* out)
{
  __shared__ __align__(16) unsigned short lw3[16 * 64 * 8];  // 16 KiB
  __shared__ __align__(16) float sb3[4 * 2048];              // 32 KiB
  __shared__ __align__(16) float lsc[C2];
  __shared__ __align__(16) float ltb[C2];
  if (probe_f32(feat)) cv3_body<true >(t, W3, feat, g3, b3, m3, v3, out, lw3, lsc, ltb, sb3);
  else                 cv3_body<false>(t, W3, feat, g3, b3, m3, v3, out, lw3, lsc, ltb, sb3);
}

// ---------------------------------------------------------------------------
extern "C" void kernel_launch(void* const* d_in, const int* in_sizes, int n_in,
                              void* d_out, int out_size, void* d_ws, size_t ws_size,
                              hipStream_t stream)
{
  (void)out_size; (void)ws_size;
  // dict order: feat(64e6B) nbr W1 W2 W3 g1 b1 m1 v1 g2 b2 m2 v2 g3 b3 m3 v3
  int mp[17];
  for (int i = 0; i < 17; ++i) mp[i] = i;
  if (n_in == 17 && in_sizes[0] != 64000000 &&
      in_sizes[6] == 64000000 && in_sizes[13] == 4500000) {
    const int amap[17] = {6, 13, 0, 1, 2, 7, 3, 10, 14, 8, 4, 11, 15, 9, 5, 12, 16};
    for (int i = 0; i < 17; ++i) mp[i] = amap[i];
  }
  const void* feat = d_in[mp[0]];
  const int*  nbr  = (const int*)d_in[mp[1]];
  const void* W1 = d_in[mp[2]];
  const void* W2 = d_in[mp[3]];
  const void* W3 = d_in[mp[4]];
  const void* g1 = d_in[mp[5]],  *b1 = d_in[mp[6]],  *m1 = d_in[mp[7]],  *v1 = d_in[mp[8]];
  const void* g2 = d_in[mp[9]],  *b2 = d_in[mp[10]], *m2 = d_in[mp[11]], *v2 = d_in[mp[12]];
  const void* g3 = d_in[mp[13]], *b3 = d_in[mp[14]], *m3 = d_in[mp[15]], *v3 = d_in[mp[16]];

  // workspace: h = N*64 bf16 row-major; t = N*64 bf16 D-natural blocked
  unsigned short* h = (unsigned short*)d_ws;
  unsigned short* t = (unsigned short*)((char*)d_ws + (size_t)N_SITES * CH * 2);
  // 128B zero row for sentinel gathers at start of d_out (zeroed by k_cv1,
  // read by k_cv2, overwritten by k_cv3).
  unsigned short* zrow = (unsigned short*)d_out;

  k_cv1<<<2048, 256, 0, stream>>>(feat, W1, g1, b1, m1, v1, h, zrow);
  k_cv2<<<1024, 512, 0, stream>>>(h, nbr, W2, g2, b2, m2, v2, t, zrow);
  k_cv3<<<2048, 256, 0, stream>>>(t, W3, feat, g3, b3, m3, v3, (void*)d_out);
}

// Round 5
// 641.789 us; speedup vs baseline: 1.5970x; 1.4381x over previous
//
#include <hip/hip_runtime.h>

#define DEVINL __device__ __forceinline__

constexpr int N_SITES = 500000;
constexpr int C1 = 128;
constexpr int CH = 64;
constexpr int C2 = 128;
constexpr float BN_EPS = 1e-5f;
constexpr int NT32 = N_SITES / 32;   // 15625 tiles of 32 sites (exact)

typedef __attribute__((ext_vector_type(4))) float f32x4;
typedef __attribute__((ext_vector_type(8))) short s16x8;

DEVINL float bf2f(unsigned short s) { return __uint_as_float(((unsigned)s) << 16); }
DEVINL unsigned short f2bf(float f) {
  unsigned u = __float_as_uint(f);
  return (unsigned short)((u + 0x7fffu + ((u >> 16) & 1u)) >> 16);  // RNE
}
DEVINL float silu_f(float x) { return x / (1.0f + __expf(-x)); }

template<bool F32>
DEVINL float rdf(const void* p, long i) {
  if constexpr (F32) return ((const float*)p)[i];
  else return bf2f(((const unsigned short*)p)[i]);
}

DEVINL bool probe_f32(const void* buf) {
  unsigned w = ((const unsigned*)buf)[threadIdx.x & 63];
  unsigned e = (w >> 7) & 0xFFu;
  bool bf_like = (e >= 90u && e <= 134u) || ((w & 0xFFFFu) == 0u);
  return __popcll(__ballot(bf_like)) < 48;
}
DEVINL bool probe_i64(const int* nbr) {
  int v = nbr[2 * (threadIdx.x & 63) + 1];
  return __popcll(__ballot(v == 0)) == 64;
}
template<bool I64>
DEVINL int rd_idx(const int* nbr, long ofs) {
  if constexpr (I64) return nbr[2 * ofs];
  else return nbr[ofs];
}

DEVINL s16x8 as_s16x8(uint4 v) { union { uint4 u; s16x8 s; } c; c.u = v; return c.s; }

DEVINL s16x8 pack8(float a0, float a1, float a2, float a3,
                   float a4, float a5, float a6, float a7) {
  uint4 r;
  r.x = (unsigned)f2bf(a0) | ((unsigned)f2bf(a1) << 16);
  r.y = (unsigned)f2bf(a2) | ((unsigned)f2bf(a3) << 16);
  r.z = (unsigned)f2bf(a4) | ((unsigned)f2bf(a5) << 16);
  r.w = (unsigned)f2bf(a6) | ((unsigned)f2bf(a7) << 16);
  return as_s16x8(r);
}

// Swapped-operand MFMA: D = A*B, A = W^T (m = out-channel), B = data^T
// (n = site).  D: lane (lg*16+lr) holds site lr, channels lg*4+q per m-tile.
DEVINL f32x4 mfma16(s16x8 a, s16x8 b, f32x4 c) {
  return __builtin_amdgcn_mfma_f32_16x16x32_bf16(a, b, c, 0, 0, 0);
}

// Weight fragment packing: element (k, n) of a [K][M] slab -> frag
// (kk = k>>5, mt = n>>4), lane = ((k>>3)&3)*16 + (n&15), j = k&7.

// ---------------------------------------------------------------------------
// K1: h = silu(bn1(features @ W1)), h bf16 [N][64] ROW-MAJOR (gather target).
// LDS-bounce epilogue -> 16B/lane ascending stores (proven-coalescing size).
// ---------------------------------------------------------------------------
template<bool F32>
DEVINL void cv1_body(const void* feat, const void* W1,
                     const void* g1, const void* b1, const void* m1, const void* v1,
                     unsigned short* __restrict__ h,
                     unsigned short* lw1, float* lsc, float* ltb,
                     unsigned short* sb /* [4 waves][16 rows][72] */)
{
  const int tid = threadIdx.x;
  for (int n = tid; n < CH; n += 256) {
    float s = rdf<F32>(g1, n) * rsqrtf(rdf<F32>(v1, n) + BN_EPS);
    lsc[n] = s;
    ltb[n] = rdf<F32>(b1, n) - rdf<F32>(m1, n) * s;
  }
  __syncthreads();
  for (int idx = tid; idx < C1 * CH; idx += 256) {
    int k = idx >> 6, n = idx & 63;
    int frag = (k >> 5) * 4 + (n >> 4);
    int ln = (((k >> 3) & 3) << 4) | (n & 15);
    lw1[(frag * 64 + ln) * 8 + (k & 7)] = f2bf(rdf<F32>(W1, idx) * lsc[n]);
  }
  __syncthreads();

  const int lane = tid & 63, w = tid >> 6;
  const int lr = lane & 15, lg = lane >> 4;
  const s16x8* lw1s = (const s16x8*)lw1;
  unsigned short* sw = sb + w * (16 * 72);
  s16x8 aw[4][4];
#pragma unroll
  for (int kk = 0; kk < 4; ++kk)
#pragma unroll
    for (int mt = 0; mt < 4; ++mt)
      aw[kk][mt] = lw1s[(kk * 4 + mt) * 64 + lane];

  const int stride = gridDim.x * 4;
  for (int tile = blockIdx.x * 4 + w; tile < NT32; tile += stride) {
    const long base = (long)tile * 32;
    f32x4 acc[2][4];
#pragma unroll
    for (int st = 0; st < 2; ++st)
#pragma unroll
      for (int mt = 0; mt < 4; ++mt) acc[st][mt] = (f32x4)0.0f;

#pragma unroll
    for (int st = 0; st < 2; ++st) {
      const long row = base + st * 16 + lr;
#pragma unroll
      for (int kk = 0; kk < 4; ++kk) {
        s16x8 b;
        if constexpr (F32) {
          const float* fp = (const float*)feat + row * C1 + kk * 32 + lg * 8;
          float4 f0 = ((const float4*)fp)[0];
          float4 f1 = ((const float4*)fp)[1];
          b = pack8(f0.x, f0.y, f0.z, f0.w, f1.x, f1.y, f1.z, f1.w);
        } else {
          b = as_s16x8(*(const uint4*)((const unsigned short*)feat + row * C1 + kk * 32 + lg * 8));
        }
#pragma unroll
        for (int mt = 0; mt < 4; ++mt)
          acc[st][mt] = mfma16(aw[kk][mt], b, acc[st][mt]);
      }
    }
#pragma unroll
    for (int st = 0; st < 2; ++st) {
      __builtin_amdgcn_wave_barrier();
#pragma unroll
      for (int mt = 0; mt < 4; ++mt) {
        int ch4 = mt * 16 + lg * 4;
        f32x4 tb = *(const f32x4*)&ltb[ch4];
        f32x4 v = acc[st][mt];
        ushort4 hv;
        hv.x = f2bf(silu_f(v[0] + tb[0]));
        hv.y = f2bf(silu_f(v[1] + tb[1]));
        hv.z = f2bf(silu_f(v[2] + tb[2]));
        hv.w = f2bf(silu_f(v[3] + tb[3]));
        *(ushort4*)(sw + lr * 72 + ch4) = hv;
      }
      __builtin_amdgcn_wave_barrier();
      uint4 r1 = *(const uint4*)(sw + (lane >> 3) * 72 + (lane & 7) * 8);
      uint4 r2 = *(const uint4*)(sw + (8 + (lane >> 3)) * 72 + (lane & 7) * 8);
      size_t ho = (size_t)(base + st * 16) * CH;
      *(uint4*)(h + ho + lane * 8) = r1;          // 16B/lane ascending
      *(uint4*)(h + ho + 512 + lane * 8) = r2;
      __builtin_amdgcn_wave_barrier();
    }
  }
}

__global__ __launch_bounds__(256, 4) void k_cv1(
    const void* feat, const void* W1,
    const void* g1, const void* b1, const void* m1, const void* v1,
    unsigned short* __restrict__ h, unsigned short* __restrict__ zrow)
{
  __shared__ __align__(16) unsigned short lw1[16 * 64 * 8];   // 16 KiB
  __shared__ __align__(16) unsigned short sb[4 * 16 * 72];    // 9.2 KiB
  __shared__ __align__(16) float lsc[CH];
  __shared__ __align__(16) float ltb[CH];
  if (blockIdx.x == 0 && threadIdx.x < 8)
    ((uint4*)zrow)[threadIdx.x] = make_uint4(0u, 0u, 0u, 0u);
  if (probe_f32(feat)) cv1_body<true >(feat, W1, g1, b1, m1, v1, h, lw1, lsc, ltb, sb);
  else                 cv1_body<false>(feat, W1, g1, b1, m1, v1, h, lw1, lsc, ltb, sb);
}

// ---------------------------------------------------------------------------
// K23 (FUSED cv2+cv3): per 32-site tile,
//   t = silu(bn2( sum_{k=0..8} gather(h, nbr[k]) @ W2[k] ))   [registers]
//   out = silu( bn3(t @ W3) + features )
// t never touches global memory: D-layout -> B-fragment permutation goes
// through a 2.3KB per-wave LDS scratch (same-wave, wave_barrier only).
// W2 frags in LDS (74KB); W3 frags in registers.  Out stores: 16B/lane.
// ---------------------------------------------------------------------------
#define CV2_ISSUE(slot, tap_) do {                                              \
    const unsigned short* s0_ = (i0[tap_] == N_SITES) ? zrow                     \
                                : h + (size_t)i0[tap_] * CH;                     \
    const unsigned short* s1_ = (i1[tap_] == N_SITES) ? zrow                     \
                                : h + (size_t)i1[tap_] * CH;                     \
    G[slot][0] = as_s16x8(*(const uint4*)(s0_ + lg * 8));                        \
    G[slot][1] = as_s16x8(*(const uint4*)(s0_ + 32 + lg * 8));                   \
    G[slot][2] = as_s16x8(*(const uint4*)(s1_ + lg * 8));                        \
    G[slot][3] = as_s16x8(*(const uint4*)(s1_ + 32 + lg * 8));                   \
  } while (0)

template<bool F32, bool I64>
DEVINL void cv23_body(const unsigned short* __restrict__ h, const int* __restrict__ nbr,
                      const void* W2, const void* W3, const void* feat,
                      const void* g2, const void* b2, const void* m2, const void* v2,
                      const void* g3, const void* b3, const void* m3, const void* v3,
                      void* out, const unsigned short* __restrict__ zrow,
                      unsigned short* lw2, unsigned short* swt,
                      float* lsc2, float* ltb2, float* lsc3, float* ltb3)
{
  const int tid = threadIdx.x;
  for (int n = tid; n < CH; n += 512) {
    float s = rdf<F32>(g2, n) * rsqrtf(rdf<F32>(v2, n) + BN_EPS);
    lsc2[n] = s;
    ltb2[n] = rdf<F32>(b2, n) - rdf<F32>(m2, n) * s;
  }
  for (int n = tid; n < C2; n += 512) {
    float s = rdf<F32>(g3, n) * rsqrtf(rdf<F32>(v3, n) + BN_EPS);
    lsc3[n] = s;
    ltb3[n] = rdf<F32>(b3, n) - rdf<F32>(m3, n) * s;
  }
  __syncthreads();
  // stage W2 -> LDS fragment order (scale-folded)
  for (int idx = tid; idx < 9 * CH * CH; idx += 512) {
    int tap = idx >> 12;
    int k = (idx >> 6) & 63, n = idx & 63;
    int frag = (tap * 2 + (k >> 5)) * 4 + (n >> 4);
    int ln = (((k >> 3) & 3) << 4) | (n & 15);
    lw2[(frag * 64 + ln) * 8 + (k & 7)] = f2bf(rdf<F32>(W2, (long)idx) * lsc2[n]);
  }

  const int lane = tid & 63, w = tid >> 6;   // w in [0,8)
  const int lr = lane & 15, lg = lane >> 4;

  // W3^T A-fragments straight into registers (scale-folded): one-time cost.
  s16x8 aw3[2][8];
#pragma unroll
  for (int kk = 0; kk < 2; ++kk)
#pragma unroll
    for (int mm = 0; mm < 8; ++mm) {
      float sc = lsc3[mm * 16 + lr];
      float e[8];
#pragma unroll
      for (int j = 0; j < 8; ++j)
        e[j] = rdf<F32>(W3, (long)(kk * 32 + lg * 8 + j) * C2 + mm * 16 + lr) * sc;
      aw3[kk][mm] = pack8(e[0], e[1], e[2], e[3], e[4], e[5], e[6], e[7]);
    }
  __syncthreads();

  const s16x8* lw2s = (const s16x8*)lw2;
  unsigned short* sw = swt + w * 2176;   // per-wave scratch (16x136 ushorts)

  const int stride = gridDim.x * 8;
  for (int tile = blockIdx.x * 8 + w; tile < NT32; tile += stride) {
    const long base = (long)tile * 32;
    int i0[9], i1[9];
#pragma unroll
    for (int tap = 0; tap < 9; ++tap) {
      i0[tap] = rd_idx<I64>(nbr, (long)tap * N_SITES + base + lr);
      i1[tap] = rd_idx<I64>(nbr, (long)tap * N_SITES + base + 16 + lr);
    }
    f32x4 acc[2][4];
#pragma unroll
    for (int st = 0; st < 2; ++st)
#pragma unroll
      for (int mt = 0; mt < 4; ++mt) acc[st][mt] = (f32x4)0.0f;

    s16x8 G[3][4];
    CV2_ISSUE(0, 0); CV2_ISSUE(1, 1); CV2_ISSUE(2, 2);
#pragma unroll
    for (int tap = 0; tap < 9; ++tap) {
      const int slot = tap % 3;
#pragma unroll
      for (int mt = 0; mt < 4; ++mt) {
        s16x8 a0 = lw2s[((tap * 2 + 0) * 4 + mt) * 64 + lane];
        s16x8 a1 = lw2s[((tap * 2 + 1) * 4 + mt) * 64 + lane];
        acc[0][mt] = mfma16(a0, G[slot][0], acc[0][mt]);
        acc[0][mt] = mfma16(a1, G[slot][1], acc[0][mt]);
        acc[1][mt] = mfma16(a0, G[slot][2], acc[1][mt]);
        acc[1][mt] = mfma16(a1, G[slot][3], acc[1][mt]);
      }
      if (tap + 3 < 9) CV2_ISSUE(slot, tap + 3);
    }

    // ---- cv3, per st half-tile (scratch reused) ----
#pragma unroll
    for (int st = 0; st < 2; ++st) {
      __builtin_amdgcn_wave_barrier();
      // t (bf16, post-silu) -> scratch rows (site-major, stride 72)
#pragma unroll
      for (int mt = 0; mt < 4; ++mt) {
        int ch4 = mt * 16 + lg * 4;
        f32x4 tbv = *(const f32x4*)&ltb2[ch4];
        f32x4 v = acc[st][mt];
        ushort4 tv;
        tv.x = f2bf(silu_f(v[0] + tbv[0]));
        tv.y = f2bf(silu_f(v[1] + tbv[1]));
        tv.z = f2bf(silu_f(v[2] + tbv[2]));
        tv.w = f2bf(silu_f(v[3] + tbv[3]));
        *(ushort4*)(sw + lr * 72 + ch4) = tv;
      }
      __builtin_amdgcn_wave_barrier();
      // B-fragments of t for the cv3 MFMA
      s16x8 bfr0 = *(const s16x8*)(sw + lr * 72 + lg * 8);
      s16x8 bfr1 = *(const s16x8*)(sw + lr * 72 + 32 + lg * 8);
      f32x4 acc3[8];
#pragma unroll
      for (int mm = 0; mm < 8; ++mm) acc3[mm] = (f32x4)0.0f;
#pragma unroll
      for (int mm = 0; mm < 8; ++mm) acc3[mm] = mfma16(aw3[0][mm], bfr0, acc3[mm]);
#pragma unroll
      for (int mm = 0; mm < 8; ++mm) acc3[mm] = mfma16(aw3[1][mm], bfr1, acc3[mm]);

      const size_t site = (size_t)(base + st * 16 + lr);
      if constexpr (F32) {
#pragma unroll
        for (int mm = 0; mm < 8; ++mm) {
          int ch4 = mm * 16 + lg * 4;
          f32x4 tbv = *(const f32x4*)&ltb3[ch4];
          float4 fv = *(const float4*)((const float*)feat + site * C1 + ch4);
          float4 ov;
          ov.x = silu_f(acc3[mm][0] + tbv[0] + fv.x);
          ov.y = silu_f(acc3[mm][1] + tbv[1] + fv.y);
          ov.z = silu_f(acc3[mm][2] + tbv[2] + fv.z);
          ov.w = silu_f(acc3[mm][3] + tbv[3] + fv.w);
          *(float4*)((float*)out + site * C2 + ch4) = ov;   // 16B/lane
        }
      } else {
        // bf16 path: bounce through scratch (stride 136) -> 16B/lane stores
        __builtin_amdgcn_wave_barrier();
#pragma unroll
        for (int mm = 0; mm < 8; ++mm) {
          int ch4 = mm * 16 + lg * 4;
          f32x4 tbv = *(const f32x4*)&ltb3[ch4];
          ushort4 ov;
          ov.x = f2bf(acc3[mm][0] + tbv[0]);
          ov.y = f2bf(acc3[mm][1] + tbv[1]);
          ov.z = f2bf(acc3[mm][2] + tbv[2]);
          ov.w = f2bf(acc3[mm][3] + tbv[3]);
          *(ushort4*)(sw + lr * 136 + ch4) = ov;
        }
        __builtin_amdgcn_wave_barrier();
#pragma unroll
        for (int p = 0; p < 4; ++p) {
          int r = p * 4 + (lane >> 4);
          int c8 = (lane & 15) * 8;
          const unsigned short* sp = sw + r * 136 + c8;
          size_t srow = (size_t)(base + st * 16 + r) * C2 + c8;
          const unsigned short* fp = (const unsigned short*)feat + srow;
          unsigned short* op = (unsigned short*)out + srow;
          ushort4 o0 = *(const ushort4*)sp, o1 = *(const ushort4*)(sp + 4);
          ushort4 f0 = *(const ushort4*)fp, f1 = *(const ushort4*)(fp + 4);
          ushort4 w0, w1;
          w0.x = f2bf(silu_f(bf2f(o0.x) + bf2f(f0.x)));
          w0.y = f2bf(silu_f(bf2f(o0.y) + bf2f(f0.y)));
          w0.z = f2bf(silu_f(bf2f(o0.z) + bf2f(f0.z)));
          w0.w = f2bf(silu_f(bf2f(o0.w) + bf2f(f0.w)));
          w1.x = f2bf(silu_f(bf2f(o1.x) + bf2f(f1.x)));
          w1.y = f2bf(silu_f(bf2f(o1.y) + bf2f(f1.y)));
          w1.z = f2bf(silu_f(bf2f(o1.z) + bf2f(f1.z)));
          w1.w = f2bf(silu_f(bf2f(o1.w) + bf2f(f1.w)));
          *(ushort4*)op = w0;
          *(ushort4*)(op + 4) = w1;
        }
        __builtin_amdgcn_wave_barrier();
      }
    }
  }
}

__global__ __launch_bounds__(512, 2) void k_cv23(
    const unsigned short* __restrict__ h, const int* __restrict__ nbr,
    const void* W2, const void* W3, const void* feat,
    const void* g2, const void* b2, const void* m2, const void* v2,
    const void* g3, const void* b3, const void* m3, const void* v3,
    void* out, const unsigned short* __restrict__ zrow)
{
  __shared__ __align__(16) unsigned short lw2[72 * 64 * 8];   // 73728 B
  __shared__ __align__(16) unsigned short swt[8 * 2176];      // 34816 B
  __shared__ __align__(16) float lsc2[CH], ltb2[CH];
  __shared__ __align__(16) float lsc3[C2], ltb3[C2];
  bool f32 = probe_f32(feat);
  bool i64 = probe_i64(nbr);
  if (f32) { if (i64) cv23_body<true , true >(h, nbr, W2, W3, feat, g2, b2, m2, v2, g3, b3, m3, v3, out, zrow, lw2, swt, lsc2, ltb2, lsc3, ltb3);
             else     cv23_body<true , false>(h, nbr, W2, W3, feat, g2, b2, m2, v2, g3, b3, m3, v3, out, zrow, lw2, swt, lsc2, ltb2, lsc3, ltb3); }
  else     { if (i64) cv23_body<false, true >(h, nbr, W2, W3, feat, g2, b2, m2, v2, g3, b3, m3, v3, out, zrow, lw2, swt, lsc2, ltb2, lsc3, ltb3);
             else     cv23_body<false, false>(h, nbr, W2, W3, feat, g2, b2, m2, v2, g3, b3, m3, v3, out, zrow, lw2, swt, lsc2, ltb2, lsc3, ltb3); }
}

// ---------------------------------------------------------------------------
extern "C" void kernel_launch(void* const* d_in, const int* in_sizes, int n_in,
                              void* d_out, int out_size, void* d_ws, size_t ws_size,
                              hipStream_t stream)
{
  (void)out_size; (void)ws_size;
  // dict order: feat(64e6B) nbr W1 W2 W3 g1 b1 m1 v1 g2 b2 m2 v2 g3 b3 m3 v3
  int mp[17];
  for (int i = 0; i < 17; ++i) mp[i] = i;
  if (n_in == 17 && in_sizes[0] != 64000000 &&
      in_sizes[6] == 64000000 && in_sizes[13] == 4500000) {
    const int amap[17] = {6, 13, 0, 1, 2, 7, 3, 10, 14, 8, 4, 11, 15, 9, 5, 12, 16};
    for (int i = 0; i < 17; ++i) mp[i] = amap[i];
  }
  const void* feat = d_in[mp[0]];
  const int*  nbr  = (const int*)d_in[mp[1]];
  const void* W1 = d_in[mp[2]];
  const void* W2 = d_in[mp[3]];
  const void* W3 = d_in[mp[4]];
  const void* g1 = d_in[mp[5]],  *b1 = d_in[mp[6]],  *m1 = d_in[mp[7]],  *v1 = d_in[mp[8]];
  const void* g2 = d_in[mp[9]],  *b2 = d_in[mp[10]], *m2 = d_in[mp[11]], *v2 = d_in[mp[12]];
  const void* g3 = d_in[mp[13]], *b3 = d_in[mp[14]], *m3 = d_in[mp[15]], *v3 = d_in[mp[16]];

  // workspace: h = N*64 bf16 row-major (64 MB); zrow = 128B zero row after it
  // (zeroed by k_cv1, read by k_cv23's sentinel gathers -- must NOT live in
  //  d_out: fused kernel writes out while other blocks still gather).
  unsigned short* h = (unsigned short*)d_ws;
  unsigned short* zrow = (unsigned short*)((char*)d_ws + (size_t)N_SITES * CH * 2);

  k_cv1<<<2048, 256, 0, stream>>>(feat, W1, g1, b1, m1, v1, h, zrow);
  k_cv23<<<256, 512, 0, stream>>>(h, nbr, W2, W3, feat,
                                  g2, b2, m2, v2, g3, b3, m3, v3,
                                  (void*)d_out, zrow);
}